// Round 1
// baseline (339.758 us; speedup 1.0000x reference)
//
#include <hip/hip_runtime.h>
#include <hip/hip_bf16.h>
#include <stddef.h>

// Problem constants
#define B_   64
#define C_   1024
#define CB_  256
#define T_   512
#define G_   8
#define N_   32768          // B_*T_
#define EPS_ 1e-5f

using short8 = __attribute__((ext_vector_type(8))) short;
using f32x4  = __attribute__((ext_vector_type(4))) float;

__device__ __forceinline__ short f2bf(float f) {
    unsigned u = __float_as_uint(f);
    u += 0x7fffu + ((u >> 16) & 1u);   // RNE
    return (short)(u >> 16);
}

__device__ __forceinline__ float mish_f(float y) {
    // mish(y) = y * tanh(softplus(y)) = y * (u^2+2u)/(u^2+2u+2), u = e^y
    float u = __expf(fminf(y, 30.f));
    float w = u * u + 2.f * u;
    return y * (w / (w + 2.f));
}

// ---------------- Kernel 0: weights fp32 -> bf16 ----------------
__global__ void prep_weights(const float* __restrict__ wd, const float* __restrict__ wu,
                             short* __restrict__ wdb, short* __restrict__ wub) {
    int i = blockIdx.x * 256 + threadIdx.x;   // 0 .. 262143
    if (i < CB_ * C_) {
        wdb[i] = f2bf(wd[i]);
        wub[i] = f2bf(wu[i]);
    }
}

// ---------------- Kernel 1: group stats -> per-(b,c) scale/shift ----------------
__global__ void stats_kernel(const float* __restrict__ x, const float* __restrict__ gamma,
                             const float* __restrict__ beta,
                             float* __restrict__ scaleW, float* __restrict__ shiftW) {
    const int tid = threadIdx.x;
    const int bg = blockIdx.x;
    const int b = bg >> 3, g = bg & 7;
    // group data is contiguous: 128 channels * 512 t = 65536 floats
    const float4* p = (const float4*)(x + ((size_t)b * C_ + g * 128) * T_);
    float s = 0.f, q = 0.f;
    for (int i = tid; i < 16384; i += 256) {
        float4 v = p[i];
        s += v.x + v.y + v.z + v.w;
        q += v.x * v.x + v.y * v.y + v.z * v.z + v.w * v.w;
    }
    // wave reduce (width 64)
    for (int o = 32; o > 0; o >>= 1) {
        s += __shfl_down(s, o);
        q += __shfl_down(q, o);
    }
    __shared__ float red[8];
    __shared__ float mr[2];
    const int wid = tid >> 6, lane = tid & 63;
    if (lane == 0) { red[wid] = s; red[4 + wid] = q; }
    __syncthreads();
    if (tid == 0) {
        float S = red[0] + red[1] + red[2] + red[3];
        float Q = red[4] + red[5] + red[6] + red[7];
        float mean = S * (1.f / 65536.f);
        float var = Q * (1.f / 65536.f) - mean * mean;
        mr[0] = mean;
        mr[1] = rsqrtf(var + EPS_);
    }
    __syncthreads();
    float mean = mr[0], rstd = mr[1];
    if (tid < 128) {
        int c = g * 128 + tid;
        float sc = rstd * gamma[c];
        scaleW[b * C_ + c] = sc;
        shiftW[b * C_ + c] = beta[c] - mean * sc;
    }
}

// ---------------- GEMM common geometry ----------------
// 128x128 tile, BK=32, 256 threads = 4 waves (2x2), each wave 64x64 = 4x4 MFMA 16x16x32.
// LDS row stride 40 bf16 (80 B = 20 dwords): conflict-free for b128 fragment reads.
#define LDSTR 40

// ---------------- Kernel 2: GEMM1 (down-proj) + groupnorm fused in staging + mish ----------------
__global__ __launch_bounds__(256, 2) void gemm1_mish(
    const float* __restrict__ x, const short* __restrict__ wd,
    const float* __restrict__ b_down,
    const float* __restrict__ scaleW, const float* __restrict__ shiftW,
    short* __restrict__ mid) {
    __shared__ short As[128 * LDSTR];
    __shared__ short Bs[128 * LDSTR];
    __shared__ float sS[C_], sT[C_];

    const int tid = threadIdx.x;
    const int n0 = blockIdx.x * 128;       // N tile (0..255)
    const int m0 = blockIdx.y * 128;       // M tile (0..1)
    const int b  = n0 >> 9;                // batch index (tile fits in one b)

    // preload scale/shift for this batch
    for (int i = tid; i < C_; i += 256) {
        sS[i] = scaleW[b * C_ + i];
        sT[i] = shiftW[b * C_ + i];
    }

    const int a_kc = tid & 3;      // k-chunk (8 bf16)
    const int a_m  = tid >> 2;     // 0..63 (rows a_m, a_m+64)
    const int b_n  = tid & 127;    // n within tile
    const int b_kg = tid >> 7;     // 0/1 -> k half (16)
    const int wid  = tid >> 6;
    const int lane = tid & 63;
    const int wm = wid >> 1, wn = wid & 1;
    const int q = lane >> 4, l16 = lane & 15;

    f32x4 acc[4][4];
#pragma unroll
    for (int i = 0; i < 4; i++)
#pragma unroll
        for (int j = 0; j < 4; j++) acc[i][j] = 0.f;

    const float* xb = x + (size_t)b * C_ * T_ + (n0 & 511);

    for (int kt = 0; kt < 32; ++kt) {
        const int k0 = kt * 32;
        __syncthreads();
        // stage A (w_down bf16, row-major [256][1024])
        {
            const short* src = wd + (m0 + a_m) * C_ + k0 + a_kc * 8;
            *(short8*)&As[a_m * LDSTR + a_kc * 8] = *(const short8*)src;
            *(short8*)&As[(a_m + 64) * LDSTR + a_kc * 8] = *(const short8*)(src + 64 * C_);
        }
        // stage B transposed: LDS[n][k], apply scale/shift, convert bf16
        {
            const int cbase = k0 + b_kg * 16;
            const float* xp = xb + (size_t)cbase * T_ + b_n;
            f32x4 ss[4], st[4];
#pragma unroll
            for (int i2 = 0; i2 < 4; i2++) {
                ss[i2] = *(const f32x4*)&sS[cbase + i2 * 4];
                st[i2] = *(const f32x4*)&sT[cbase + i2 * 4];
            }
            short8 v0, v1;
#pragma unroll
            for (int i = 0; i < 8; i++) {
                float h0 = xp[(size_t)i * T_] * ss[i >> 2][i & 3] + st[i >> 2][i & 3];
                v0[i] = f2bf(h0);
            }
#pragma unroll
            for (int i = 0; i < 8; i++) {
                int k = i + 8;
                float h1 = xp[(size_t)k * T_] * ss[k >> 2][k & 3] + st[k >> 2][k & 3];
                v1[i] = f2bf(h1);
            }
            *(short8*)&Bs[b_n * LDSTR + b_kg * 16] = v0;
            *(short8*)&Bs[b_n * LDSTR + b_kg * 16 + 8] = v1;
        }
        __syncthreads();
        short8 af[4], bfr[4];
#pragma unroll
        for (int i = 0; i < 4; i++)
            af[i] = *(const short8*)&As[(wm * 64 + i * 16 + l16) * LDSTR + q * 8];
#pragma unroll
        for (int j = 0; j < 4; j++)
            bfr[j] = *(const short8*)&Bs[(wn * 64 + j * 16 + l16) * LDSTR + q * 8];
#pragma unroll
        for (int i = 0; i < 4; i++)
#pragma unroll
            for (int j = 0; j < 4; j++)
                acc[i][j] = __builtin_amdgcn_mfma_f32_16x16x32_bf16(af[i], bfr[j], acc[i][j], 0, 0, 0);
    }
    // epilogue: + b_down, mish, store bf16 mid[o][n]
#pragma unroll
    for (int i = 0; i < 4; i++) {
        const int o_b = m0 + wm * 64 + i * 16 + q * 4;
#pragma unroll
        for (int j = 0; j < 4; j++) {
            const int n = n0 + wn * 64 + j * 16 + l16;
#pragma unroll
            for (int r = 0; r < 4; r++) {
                const int o = o_b + r;
                float y = acc[i][j][r] + b_down[o];
                mid[(size_t)o * N_ + n] = f2bf(mish_f(y));
            }
        }
    }
}

// ---------------- Kernel 3: GEMM2 (up-proj) + bias + residual ----------------
__global__ __launch_bounds__(256, 2) void gemm2_resid(
    const short* __restrict__ mid, const short* __restrict__ wu,
    const float* __restrict__ b_up, const float* __restrict__ x,
    float* __restrict__ out) {
    __shared__ short As[128 * LDSTR];
    __shared__ short Bs[128 * LDSTR];

    const int tid = threadIdx.x;
    const int n0 = blockIdx.x * 128;       // 0..255
    const int m0 = blockIdx.y * 128;       // 0..7

    const int a_kc = tid & 3;
    const int a_m  = tid >> 2;
    const int b_n  = tid & 127;
    const int b_kg = tid >> 7;
    const int wid  = tid >> 6;
    const int lane = tid & 63;
    const int wm = wid >> 1, wn = wid & 1;
    const int q = lane >> 4, l16 = lane & 15;

    f32x4 acc[4][4];
#pragma unroll
    for (int i = 0; i < 4; i++)
#pragma unroll
        for (int j = 0; j < 4; j++) acc[i][j] = 0.f;

    for (int kt = 0; kt < 8; ++kt) {   // K=256, BK=32
        const int k0 = kt * 32;
        __syncthreads();
        // stage A (w_up bf16 [1024][256])
        {
            const short* src = wu + (m0 + a_m) * CB_ + k0 + a_kc * 8;
            *(short8*)&As[a_m * LDSTR + a_kc * 8] = *(const short8*)src;
            *(short8*)&As[(a_m + 64) * LDSTR + a_kc * 8] = *(const short8*)(src + 64 * CB_);
        }
        // stage B transposed: mid[k][n] -> LDS[n][k]
        {
            const short* mp = mid + (size_t)(k0 + b_kg * 16) * N_ + n0 + b_n;
            short8 v0, v1;
#pragma unroll
            for (int i = 0; i < 8; i++) v0[i] = mp[(size_t)i * N_];
#pragma unroll
            for (int i = 0; i < 8; i++) v1[i] = mp[(size_t)(i + 8) * N_];
            *(short8*)&Bs[b_n * LDSTR + b_kg * 16] = v0;
            *(short8*)&Bs[b_n * LDSTR + b_kg * 16 + 8] = v1;
        }
        __syncthreads();
        short8 af[4], bfr[4];
#pragma unroll
        for (int i = 0; i < 4; i++)
            af[i] = *(const short8*)&As[(wm * 64 + i * 16 + l16) * LDSTR + q * 8];
#pragma unroll
        for (int j = 0; j < 4; j++)
            bfr[j] = *(const short8*)&Bs[(wn * 64 + j * 16 + l16) * LDSTR + q * 8];
#pragma unroll
        for (int i = 0; i < 4; i++)
#pragma unroll
            for (int j = 0; j < 4; j++)
                acc[i][j] = __builtin_amdgcn_mfma_f32_16x16x32_bf16(af[i], bfr[j], acc[i][j], 0, 0, 0);
    }
    // epilogue: + b_up[c] + x, fp32 store
    const int b = n0 >> 9;
    const int t0 = n0 & 511;
#pragma unroll
    for (int i = 0; i < 4; i++) {
        const int c_b = m0 + wm * 64 + i * 16 + q * 4;
#pragma unroll
        for (int j = 0; j < 4; j++) {
            const int tt = t0 + wn * 64 + j * 16 + l16;
#pragma unroll
            for (int r = 0; r < 4; r++) {
                const int c = c_b + r;
                const size_t gi = ((size_t)b * C_ + c) * T_ + tt;
                out[gi] = acc[i][j][r] + b_up[c] + x[gi];
            }
        }
    }
}

// ---------------- Launch ----------------
extern "C" void kernel_launch(void* const* d_in, const int* in_sizes, int n_in,
                              void* d_out, int out_size, void* d_ws, size_t ws_size,
                              hipStream_t stream) {
    const float* x      = (const float*)d_in[0];
    const float* gamma  = (const float*)d_in[1];
    const float* beta   = (const float*)d_in[2];
    const float* w_down = (const float*)d_in[3];
    const float* b_down = (const float*)d_in[4];
    const float* w_up   = (const float*)d_in[5];
    const float* b_up   = (const float*)d_in[6];
    float* out = (float*)d_out;

    // workspace layout
    float* scaleW = (float*)d_ws;                       // B_*C_ floats
    float* shiftW = scaleW + B_ * C_;                   // B_*C_ floats
    short* wdb    = (short*)(shiftW + B_ * C_);         // CB_*C_ bf16
    short* wub    = wdb + CB_ * C_;                     // C_*CB_ bf16
    short* mid    = wub + C_ * CB_;                     // CB_*N_ bf16 (16.8 MB)

    prep_weights<<<dim3((CB_ * C_ + 255) / 256), 256, 0, stream>>>(w_down, w_up, wdb, wub);
    stats_kernel<<<dim3(B_ * G_), 256, 0, stream>>>(x, gamma, beta, scaleW, shiftW);
    gemm1_mish<<<dim3(N_ / 128, CB_ / 128), 256, 0, stream>>>(x, wdb, b_down, scaleW, shiftW, mid);
    gemm2_resid<<<dim3(N_ / 128, C_ / 128), 256, 0, stream>>>(mid, wub, b_up, x, out);
}

// Round 2
// 331.168 us; speedup vs baseline: 1.0259x; 1.0259x over previous
//
#include <hip/hip_runtime.h>
#include <hip/hip_bf16.h>
#include <stddef.h>

// Problem constants
#define B_   64
#define C_   1024
#define CB_  256
#define T_   512
#define G_   8
#define N_   32768          // B_*T_
#define EPS_ 1e-5f

using short8 = __attribute__((ext_vector_type(8))) short;
using f32x4  = __attribute__((ext_vector_type(4))) float;

__device__ __forceinline__ short f2bf(float f) {
    unsigned u = __float_as_uint(f);
    u += 0x7fffu + ((u >> 16) & 1u);   // RNE
    return (short)(u >> 16);
}

__device__ __forceinline__ float mish_f(float y) {
    // mish(y) = y * tanh(softplus(y)) = y * (u^2+2u)/(u^2+2u+2), u = e^y
    float u = __expf(fminf(y, 30.f));
    float w = u * u + 2.f * u;
    return y * (w / (w + 2.f));
}

// ---------------- Kernel 0: weights fp32 -> bf16 ----------------
__global__ void prep_weights(const float* __restrict__ wd, const float* __restrict__ wu,
                             short* __restrict__ wdb, short* __restrict__ wub) {
    int i = blockIdx.x * 256 + threadIdx.x;
    if (i < CB_ * C_) {
        wdb[i] = f2bf(wd[i]);
        wub[i] = f2bf(wu[i]);
    }
}

// ---------------- Kernel 1: group stats -> per-(b,c) scale/shift ----------------
__global__ void stats_kernel(const float* __restrict__ x, const float* __restrict__ gamma,
                             const float* __restrict__ beta,
                             float* __restrict__ scaleW, float* __restrict__ shiftW) {
    const int tid = threadIdx.x;
    const int bg = blockIdx.x;
    const int b = bg >> 3, g = bg & 7;
    const float4* p = (const float4*)(x + ((size_t)b * C_ + g * 128) * T_);
    float s = 0.f, q = 0.f;
    for (int i = tid; i < 16384; i += 256) {
        float4 v = p[i];
        s += v.x + v.y + v.z + v.w;
        q += v.x * v.x + v.y * v.y + v.z * v.z + v.w * v.w;
    }
    for (int o = 32; o > 0; o >>= 1) {
        s += __shfl_down(s, o);
        q += __shfl_down(q, o);
    }
    __shared__ float red[8];
    __shared__ float mr[2];
    const int wid = tid >> 6, lane = tid & 63;
    if (lane == 0) { red[wid] = s; red[4 + wid] = q; }
    __syncthreads();
    if (tid == 0) {
        float S = red[0] + red[1] + red[2] + red[3];
        float Q = red[4] + red[5] + red[6] + red[7];
        float mean = S * (1.f / 65536.f);
        float var = Q * (1.f / 65536.f) - mean * mean;
        mr[0] = mean;
        mr[1] = rsqrtf(var + EPS_);
    }
    __syncthreads();
    float mean = mr[0], rstd = mr[1];
    if (tid < 128) {
        int c = g * 128 + tid;
        float sc = rstd * gamma[c];
        scaleW[b * C_ + c] = sc;
        shiftW[b * C_ + c] = beta[c] - mean * sc;
    }
}

// LDS row stride 40 bf16 (80 B = 20 dwords): conflict-free for b128 fragment reads.
#define LDSTR 40

// ---------------- Kernel 2: GEMM1 (down-proj, FULL M=256 per block) + GN fused + mish ----------
// 512 threads = 8 waves (4 wm x 2 wn), each wave 64x64. Block tile 256m x 128n.
// x read exactly once across the grid (grid = 256 n-tiles = 1 block/CU).
__global__ __launch_bounds__(512, 2) void gemm1_mish(
    const float* __restrict__ x, const short* __restrict__ wd,
    const float* __restrict__ b_down,
    const float* __restrict__ scaleW, const float* __restrict__ shiftW,
    short* __restrict__ mid) {
    __shared__ short As[256 * LDSTR];   // 20.0 KB
    __shared__ short Bs[128 * LDSTR];   // 10.0 KB
    __shared__ float sS[C_], sT[C_];    //  8.0 KB

    const int tid = threadIdx.x;
    const int n0 = blockIdx.x * 128;
    const int b  = n0 >> 9;

    for (int i = tid; i < C_; i += 512) {
        sS[i] = scaleW[b * C_ + i];
        sT[i] = shiftW[b * C_ + i];
    }

    // A staging: 256 rows x 4 k-chunks(8) = 1024 short8; 512 thr -> 2 each
    const int a_kc = tid & 3;
    const int a_m  = tid >> 2;          // 0..127 (rows a_m, a_m+128)
    // B staging: 128 n x 32 k floats; thread: n=b_n, k octet b_kg*8
    const int b_n  = tid & 127;
    const int b_kg = tid >> 7;          // 0..3
    const int wid  = tid >> 6;
    const int lane = tid & 63;
    const int wm = wid >> 1, wn = wid & 1;   // wm 0..3, wn 0..1
    const int q = lane >> 4, l16 = lane & 15;

    f32x4 acc[4][4];
#pragma unroll
    for (int i = 0; i < 4; i++)
#pragma unroll
        for (int j = 0; j < 4; j++) acc[i][j] = 0.f;

    const float* xb = x + (size_t)b * C_ * T_ + (n0 & 511);

    // ---- prologue: global loads for kt=0 ----
    short8 a0, a1;
    float bv[8];
    {
        const short* src = wd + a_m * C_ + a_kc * 8;
        a0 = *(const short8*)src;
        a1 = *(const short8*)(src + 128 * C_);
        const float* xp = xb + (size_t)(b_kg * 8) * T_ + b_n;
#pragma unroll
        for (int i = 0; i < 8; i++) bv[i] = xp[(size_t)i * T_];
    }
    __syncthreads();   // sS/sT ready
    // write kt=0 to LDS
    {
        *(short8*)&As[a_m * LDSTR + a_kc * 8] = a0;
        *(short8*)&As[(a_m + 128) * LDSTR + a_kc * 8] = a1;
        short8 v;
        const int kb = b_kg * 8;
#pragma unroll
        for (int i = 0; i < 8; i++) v[i] = f2bf(bv[i] * sS[kb + i] + sT[kb + i]);
        *(short8*)&Bs[b_n * LDSTR + kb] = v;
    }
    __syncthreads();

    for (int kt = 0; kt < 32; ++kt) {
        // prefetch kt+1
        if (kt < 31) {
            const int k1 = (kt + 1) * 32;
            const short* src = wd + a_m * C_ + k1 + a_kc * 8;
            a0 = *(const short8*)src;
            a1 = *(const short8*)(src + 128 * C_);
            const float* xp = xb + (size_t)(k1 + b_kg * 8) * T_ + b_n;
#pragma unroll
            for (int i = 0; i < 8; i++) bv[i] = xp[(size_t)i * T_];
        }
        // compute kt
        short8 af[4], bfr[4];
#pragma unroll
        for (int i = 0; i < 4; i++)
            af[i] = *(const short8*)&As[(wm * 64 + i * 16 + l16) * LDSTR + q * 8];
#pragma unroll
        for (int j = 0; j < 4; j++)
            bfr[j] = *(const short8*)&Bs[(wn * 64 + j * 16 + l16) * LDSTR + q * 8];
#pragma unroll
        for (int i = 0; i < 4; i++)
#pragma unroll
            for (int j = 0; j < 4; j++)
                acc[i][j] = __builtin_amdgcn_mfma_f32_16x16x32_bf16(af[i], bfr[j], acc[i][j], 0, 0, 0);
        __syncthreads();   // all waves done reading LDS tile kt
        if (kt < 31) {
            *(short8*)&As[a_m * LDSTR + a_kc * 8] = a0;
            *(short8*)&As[(a_m + 128) * LDSTR + a_kc * 8] = a1;
            short8 v;
            const int kb = (kt + 1) * 32 + b_kg * 8;
            const int kl = b_kg * 8;
#pragma unroll
            for (int i = 0; i < 8; i++) v[i] = f2bf(bv[i] * sS[kb + i] + sT[kb + i]);
            *(short8*)&Bs[b_n * LDSTR + kl] = v;
        }
        __syncthreads();
    }

    // epilogue: + b_down, mish, store bf16 mid[o][n]
#pragma unroll
    for (int i = 0; i < 4; i++) {
        const int o_b = wm * 64 + i * 16 + q * 4;
#pragma unroll
        for (int j = 0; j < 4; j++) {
            const int n = n0 + wn * 64 + j * 16 + l16;
#pragma unroll
            for (int r = 0; r < 4; r++) {
                const int o = o_b + r;
                float y = acc[i][j][r] + b_down[o];
                mid[(size_t)o * N_ + n] = f2bf(mish_f(y));
            }
        }
    }
}

// ---------------- Kernel 3: GEMM2 (up-proj) + bias + residual ----------------
// grid (m fastest, n second) so the 8 m-blocks sharing a mid n-slice are temporally adjacent.
__global__ __launch_bounds__(256, 2) void gemm2_resid(
    const short* __restrict__ mid, const short* __restrict__ wu,
    const float* __restrict__ b_up, const float* __restrict__ x,
    float* __restrict__ out) {
    __shared__ short As[128 * LDSTR];
    __shared__ short Bs[128 * LDSTR];

    const int tid = threadIdx.x;
    const int m0 = blockIdx.x * 128;       // 0..7 (fastest)
    const int n0 = blockIdx.y * 128;       // 0..255

    const int a_kc = tid & 3;
    const int a_m  = tid >> 2;             // 0..63 (+64)
    // B staging: each thread loads ushort2 (2 n) x 8 k
    const int b_np = tid & 63;             // n pair: n = b_np*2, b_np*2+1
    const int b_kg = tid >> 6;             // 0..3 -> k octet
    const int wid  = tid >> 6;
    const int lane = tid & 63;
    const int wm = wid >> 1, wn = wid & 1;
    const int q = lane >> 4, l16 = lane & 15;

    f32x4 acc[4][4];
#pragma unroll
    for (int i = 0; i < 4; i++)
#pragma unroll
        for (int j = 0; j < 4; j++) acc[i][j] = 0.f;

    // prologue kt=0
    short8 a0, a1;
    ushort2 bv[8];
    {
        const short* src = wu + (m0 + a_m) * CB_ + a_kc * 8;
        a0 = *(const short8*)src;
        a1 = *(const short8*)(src + 64 * CB_);
        const unsigned short* mp = (const unsigned short*)mid + (size_t)(b_kg * 8) * N_ + n0 + b_np * 2;
#pragma unroll
        for (int i = 0; i < 8; i++) bv[i] = *(const ushort2*)(mp + (size_t)i * N_);
    }
    {
        *(short8*)&As[a_m * LDSTR + a_kc * 8] = a0;
        *(short8*)&As[(a_m + 64) * LDSTR + a_kc * 8] = a1;
        short8 v0, v1;
#pragma unroll
        for (int i = 0; i < 8; i++) { v0[i] = (short)bv[i].x; v1[i] = (short)bv[i].y; }
        *(short8*)&Bs[(b_np * 2) * LDSTR + b_kg * 8] = v0;
        *(short8*)&Bs[(b_np * 2 + 1) * LDSTR + b_kg * 8] = v1;
    }
    __syncthreads();

    for (int kt = 0; kt < 8; ++kt) {   // K=256, BK=32
        if (kt < 7) {
            const int k1 = (kt + 1) * 32;
            const short* src = wu + (m0 + a_m) * CB_ + k1 + a_kc * 8;
            a0 = *(const short8*)src;
            a1 = *(const short8*)(src + 64 * CB_);
            const unsigned short* mp = (const unsigned short*)mid + (size_t)(k1 + b_kg * 8) * N_ + n0 + b_np * 2;
#pragma unroll
            for (int i = 0; i < 8; i++) bv[i] = *(const ushort2*)(mp + (size_t)i * N_);
        }
        short8 af[4], bfr[4];
#pragma unroll
        for (int i = 0; i < 4; i++)
            af[i] = *(const short8*)&As[(wm * 64 + i * 16 + l16) * LDSTR + q * 8];
#pragma unroll
        for (int j = 0; j < 4; j++)
            bfr[j] = *(const short8*)&Bs[(wn * 64 + j * 16 + l16) * LDSTR + q * 8];
#pragma unroll
        for (int i = 0; i < 4; i++)
#pragma unroll
            for (int j = 0; j < 4; j++)
                acc[i][j] = __builtin_amdgcn_mfma_f32_16x16x32_bf16(af[i], bfr[j], acc[i][j], 0, 0, 0);
        __syncthreads();
        if (kt < 7) {
            *(short8*)&As[a_m * LDSTR + a_kc * 8] = a0;
            *(short8*)&As[(a_m + 64) * LDSTR + a_kc * 8] = a1;
            short8 v0, v1;
#pragma unroll
            for (int i = 0; i < 8; i++) { v0[i] = (short)bv[i].x; v1[i] = (short)bv[i].y; }
            *(short8*)&Bs[(b_np * 2) * LDSTR + b_kg * 8] = v0;
            *(short8*)&Bs[(b_np * 2 + 1) * LDSTR + b_kg * 8] = v1;
        }
        __syncthreads();
    }

    // epilogue: + b_up[c] + x, fp32 store
    const int b = n0 >> 9;
    const int t0 = n0 & 511;
#pragma unroll
    for (int i = 0; i < 4; i++) {
        const int c_b = m0 + wm * 64 + i * 16 + q * 4;
#pragma unroll
        for (int j = 0; j < 4; j++) {
            const int tt = t0 + wn * 64 + j * 16 + l16;
#pragma unroll
            for (int r = 0; r < 4; r++) {
                const int c = c_b + r;
                const size_t gi = ((size_t)b * C_ + c) * T_ + tt;
                out[gi] = acc[i][j][r] + b_up[c] + x[gi];
            }
        }
    }
}

// ---------------- Launch ----------------
extern "C" void kernel_launch(void* const* d_in, const int* in_sizes, int n_in,
                              void* d_out, int out_size, void* d_ws, size_t ws_size,
                              hipStream_t stream) {
    const float* x      = (const float*)d_in[0];
    const float* gamma  = (const float*)d_in[1];
    const float* beta   = (const float*)d_in[2];
    const float* w_down = (const float*)d_in[3];
    const float* b_down = (const float*)d_in[4];
    const float* w_up   = (const float*)d_in[5];
    const float* b_up   = (const float*)d_in[6];
    float* out = (float*)d_out;

    float* scaleW = (float*)d_ws;                       // B_*C_ floats
    float* shiftW = scaleW + B_ * C_;                   // B_*C_ floats
    short* wdb    = (short*)(shiftW + B_ * C_);         // CB_*C_ bf16
    short* wub    = wdb + CB_ * C_;                     // C_*CB_ bf16
    short* mid    = wub + C_ * CB_;                     // CB_*N_ bf16 (16.8 MB)

    prep_weights<<<dim3((CB_ * C_ + 255) / 256), 256, 0, stream>>>(w_down, w_up, wdb, wub);
    stats_kernel<<<dim3(B_ * G_), 256, 0, stream>>>(x, gamma, beta, scaleW, shiftW);
    gemm1_mish<<<dim3(N_ / 128), 512, 0, stream>>>(x, wdb, b_down, scaleW, shiftW, mid);
    gemm2_resid<<<dim3(C_ / 128, N_ / 128), 256, 0, stream>>>(mid, wub, b_up, x, out);
}